// Round 20
// baseline (492.407 us; speedup 1.0000x reference)
//
#include <hip/hip_runtime.h>
#include <hip/hip_fp16.h>
#include <math.h>

// Problem constants: B=8, Tt=16, C=1, H=W=512, 4 in-channels, 10 T-planes.
#define Bd 8
#define Td 16
#define Hd 512
#define Wd 512
#define HWc (Hd * Wd)          // 262144
#define NPIX (Bd * HWc)        // 2,097,152

// ---------------- conv tiling: 16x16 tile, 1 px/thread, 256 threads ----------
#define CT  16
#define CR  18
#define CP  20
#define CTH2 256

// ---------------- fused kernel: 128x64 core, halo 6, fp16-pair LDS state -----
#define WCR 128                // core rows
#define WCC 64                 // core cols
#define WH  6                  // halo
#define WTR 140                // region rows
#define WTC 76                 // region cols = 38 pairs
#define NPR 38                 // column pairs
#define LP2 41                 // LDS row pitch in u32 (bank-spread)
#define FTH 1024
#define PRPG 6                 // owned rows per thread
#define PNG 26                 // row groups (26*6 = 156 >= 138 interior rows)

// v_fma_mix_f32: acc(f32) += x.f16[xs] * t.f16[ts]; both srcs packed-fp16.
#define FMIX_LL(acc, xv, tv) \
    asm("v_fma_mix_f32 %0, %1, %2, %0 op_sel:[0,0,0] op_sel_hi:[1,1,0]" \
        : "+v"(acc) : "v"(xv), "v"(tv))
#define FMIX_LH(acc, xv, tv) \
    asm("v_fma_mix_f32 %0, %1, %2, %0 op_sel:[0,1,0] op_sel_hi:[1,1,0]" \
        : "+v"(acc) : "v"(xv), "v"(tv))
#define FMIX_HL(acc, xv, tv) \
    asm("v_fma_mix_f32 %0, %1, %2, %0 op_sel:[1,0,0] op_sel_hi:[1,1,0]" \
        : "+v"(acc) : "v"(xv), "v"(tv))
#define FMIX_HH(acc, xv, tv) \
    asm("v_fma_mix_f32 %0, %1, %2, %0 op_sel:[1,1,0] op_sel_hi:[1,1,0]" \
        : "+v"(acc) : "v"(xv), "v"(tv))

__device__ __forceinline__ float hi_half_f32(unsigned h) {
    __half2 hh = *(__half2*)&h;
    return __half2float(__high2half(hh));
}
__device__ __forceinline__ unsigned pack2(float a, float b) {
    __half2 h = __floats2half2_rn(a, b);
    return *(unsigned*)&h;
}

// ---------------------------------------------------------------------------
// Kernel 1 (r17 proven): o-outer conv, 1 px/thread, contiguous weight loads.
// T = conv2d(x[:,-4:,0],W)+b fused with xt0 -> out[:,0].
// T stored as half2 pairs: plane q holds (T[2q], T[2q+1]); layout (B,5,H,W).
// ---------------------------------------------------------------------------
__global__ __launch_bounds__(CTH2)
void conv_step0_kernel(const float* __restrict__ x,
                       const float* __restrict__ Wu,
                       const float* __restrict__ bu,
                       __half2* __restrict__ T,
                       float* __restrict__ out) {
    __shared__ float sX[4][CR][CP];     // 5.76 KB

    int bx  = blockIdx.x;               // 8192 = 8 b * 32 * 32 tiles
    int b   = bx >> 10;
    int rem = bx & 1023;
    int by  = rem >> 5;
    int bc  = rem & 31;
    int i0  = by * CT;
    int j0  = bc * CT;

    const float* xb = x + ((size_t)b * Td + 12) * HWc;
    int tid = threadIdx.x;

    for (int idx = tid; idx < 4 * CR * CR; idx += CTH2) {
        int ch = idx / (CR * CR);
        int r2 = idx - ch * (CR * CR);
        int r  = r2 / CR;
        int c  = r2 - r * CR;
        int gi = i0 + r - 1, gj = j0 + c - 1;
        float v = 0.0f;
        if ((unsigned)gi < (unsigned)Hd && (unsigned)gj < (unsigned)Wd)
            v = xb[(size_t)ch * HWc + gi * Wd + gj];
        sX[ch][r][c] = v;
    }
    __syncthreads();

    int tx = tid & 15;
    int ty = tid >> 4;

    float xf[36];
    #pragma unroll
    for (int ch = 0; ch < 4; ++ch)
        #pragma unroll
        for (int kh = 0; kh < 3; ++kh)
            #pragma unroll
            for (int kw = 0; kw < 3; ++kw)
                xf[(ch * 3 + kh) * 3 + kw] = sX[ch][ty + kh][tx + kw];

    int gi = i0 + ty;
    int gj = j0 + tx;
    size_t pix = (size_t)gi * Wd + gj;
    __half2* Tb = T + (size_t)b * 5 * HWc;

    float o0 = 0.0f;
    float accPrev = 0.0f;
    #pragma unroll
    for (int o = 0; o < 10; ++o) {
        const float* wo = Wu + o * 36;  // contiguous -> batched s_load
        float acc = bu[o];
        #pragma unroll
        for (int z = 0; z < 36; ++z)
            acc += xf[z] * wo[z];

        if (o < 9)
            o0 += xf[(3 * 3 + (o % 3)) * 3 + (o / 3)] * acc;
        else
            o0 += acc;

        if (o & 1) {
            __half2 h = __floats2half2_rn(accPrev, acc);
            *(unsigned*)(Tb + (size_t)(o >> 1) * HWc + pix) = *(unsigned*)&h;
        }
        accPrev = acc;
    }

    out[(size_t)b * Td * HWc + pix] = o0;
}

// ---------------------------------------------------------------------------
// Kernel 2: one scan-body iteration = 6 fused stencil steps; x state lives in
// LDS as PACKED fp16 pairs (one ds_read_b32 = 2 columns; v_fma_mix reads both
// operands' fp16 halves, f32 accumulate). Thread owns a 2-col x 6-row strip.
// Pairs never straddle the image edge (rj and 512 both even). Edge pairs
// (u=0/37) write only the interior half (ds_write_b16). Ring never written;
// contamination <=1 px/step; halo 6 protects the 128x64 core. Sigmoid at even
// sub-steps; out-of-image pixels forced 0 each step. Step 6 stores the core
// directly to global as float2 (core pairs always fully in-image).
// 256 blocks = 1/CU, one round. LDS 2 x 22.96 KB; VGPR ~90 < 128 cap (1024,2).
// ---------------------------------------------------------------------------
__global__ __launch_bounds__(FTH, 2)
void fused6_pk_kernel(const float* __restrict__ xin,   // out slot t-1 base
                      const __half2* __restrict__ T,
                      float* __restrict__ xout) {      // out slot t base
    __shared__ unsigned sA2[WTR * LP2];   // 22.96 KB (fp16 pairs)
    __shared__ unsigned sB2[WTR * LP2];

    int tile = blockIdx.x;          // 256 = 8 b * 4 tr * 8 tc
    int b  = tile >> 5;
    int tr = (tile >> 3) & 3;
    int tc = tile & 7;
    int ri = tr * WCR - WH;
    int rj = tc * WCC - WH;         // even

    const float* xb = xin + (size_t)b * Td * HWc;
    const __half2* Tb = T + (size_t)b * 5 * HWc;
    float* ob = xout + (size_t)b * Td * HWc;
    int tid = threadIdx.x;

    // Stage sA2: pack 2 cols per u32 (zeros outside image; pairs never
    // straddle the edge since rj and 512 are even).
    for (int idx = tid; idx < WTR * NPR; idx += FTH) {
        int r = idx / NPR, u = idx - r * NPR;
        int gi = ri + r, gj0 = rj + 2 * u;
        unsigned v = 0u;
        if ((unsigned)gi < (unsigned)Hd && (unsigned)gj0 < (unsigned)Wd) {
            float2 f = *(const float2*)(xb + gi * Wd + gj0);
            v = pack2(f.x, f.y);
        }
        sA2[r * LP2 + u] = v;
    }
    // Zero sB2's ring: rows 0/139 fully; pairs 0 and 37 on every row
    // (their interior halves are rewritten each step before being read).
    for (int idx = tid; idx < 2 * NPR; idx += FTH) {
        int r = (idx < NPR) ? 0 : (WTR - 1);
        int u = (idx < NPR) ? idx : idx - NPR;
        sB2[r * LP2 + u] = 0u;
    }
    for (int idx = tid; idx < 2 * WTR; idx += FTH) {
        int r = (idx < WTR) ? idx : idx - WTR;
        int u = (idx < WTR) ? 0 : (NPR - 1);
        sB2[r * LP2 + u] = 0u;
    }

    int g = tid / NPR;              // row group (0..25 active)
    int u = tid - g * NPR;          // pair index 0..37
    bool active = (g < PNG);
    int rs = 1 + g * PRPG;          // first owned row (1..151; rows >138 masked)
    int gj0 = rj + 2 * u;
    bool pairin = (unsigned)gj0 < (unsigned)Wd;   // pair fully in-image
    int uL = (u == 0) ? 0 : u - 1;                // clamped; feeds masked output
    int uR = (u == NPR - 1) ? (NPR - 1) : u + 1;

    // T coefs: uint2 = both pixels' half2 per plane per row (8B aligned).
    unsigned tA[PRPG][5], tB[PRPG][5];
    #pragma unroll
    for (int jj = 0; jj < PRPG; ++jj) {
        int r  = rs + jj;
        int gi = ri + r;
        bool ok = active && (r <= WTR - 2) && ((unsigned)gi < (unsigned)Hd) && pairin;
        #pragma unroll
        for (int q = 0; q < 5; ++q) {
            uint2 pk; pk.x = 0u; pk.y = 0u;
            if (ok) pk = *(const uint2*)(Tb + (size_t)q * HWc + gi * Wd + gj0);
            tA[jj][q] = pk.x;
            tB[jj][q] = pk.y;
        }
    }
    __syncthreads();

    unsigned* cur = sA2;
    unsigned* nxt = sB2;

    #pragma unroll
    for (int s = 1; s <= 6; ++s) {
        if (active) {
            // Streaming 3-row window of packed pairs: A = pair u-1, B = u, C = u+1.
            int base = (rs - 1) * LP2;
            unsigned Ap = cur[base + uL], Bp = cur[base + u], Cp = cur[base + uR];
            base += LP2;
            unsigned Ac = cur[base + uL], Bc = cur[base + u], Cc = cur[base + uR];
            #pragma unroll
            for (int jj = 0; jj < PRPG; ++jj) {
                int r  = rs + jj;
                int rn = (r + 1 <= WTR - 1) ? (r + 1) : (WTR - 1);
                int bn = rn * LP2;
                unsigned An = cur[bn + uL], Bn = cur[bn + u], Cn = cur[bn + uR];

                // k = dj*3+di multiplies x[r+di-1][c+dj-1]; di: p=0,c=1,n=2.
                // px0 (col 2u): taps A.hi (dj0), B.lo (dj1), B.hi (dj2).
                float a0 = hi_half_f32(tA[jj][4]);     // T9
                FMIX_HL(a0, Ap, tA[jj][0]);            // k0
                FMIX_HH(a0, Ac, tA[jj][0]);            // k1
                FMIX_HL(a0, An, tA[jj][1]);            // k2
                FMIX_LH(a0, Bp, tA[jj][1]);            // k3
                FMIX_LL(a0, Bc, tA[jj][2]);            // k4
                FMIX_LH(a0, Bn, tA[jj][2]);            // k5
                FMIX_HL(a0, Bp, tA[jj][3]);            // k6
                FMIX_HH(a0, Bc, tA[jj][3]);            // k7
                FMIX_HL(a0, Bn, tA[jj][4]);            // k8
                // px1 (col 2u+1): taps B.lo (dj0), B.hi (dj1), C.lo (dj2).
                float a1 = hi_half_f32(tB[jj][4]);     // T9
                FMIX_LL(a1, Bp, tB[jj][0]);            // k0
                FMIX_LH(a1, Bc, tB[jj][0]);            // k1
                FMIX_LL(a1, Bn, tB[jj][1]);            // k2
                FMIX_HH(a1, Bp, tB[jj][1]);            // k3
                FMIX_HL(a1, Bc, tB[jj][2]);            // k4
                FMIX_HH(a1, Bn, tB[jj][2]);            // k5
                FMIX_LL(a1, Cp, tB[jj][3]);            // k6
                FMIX_LH(a1, Cc, tB[jj][3]);            // k7
                FMIX_LL(a1, Cn, tB[jj][4]);            // k8

                if ((s & 1) == 0) {
                    a0 = 1.0f / (1.0f + __expf(-a0));
                    a1 = 1.0f / (1.0f + __expf(-a1));
                }

                int gi = ri + r;
                bool inimg = ((unsigned)gi < (unsigned)Hd) && pairin;
                float v0 = inimg ? a0 : 0.0f;
                float v1 = inimg ? a1 : 0.0f;

                if (s < 6) {
                    if (r <= WTR - 2) {
                        int cell = r * LP2 + u;
                        if (u >= 1 && u <= NPR - 2) {
                            nxt[cell] = pack2(v0, v1);
                        } else if (u == 0) {
                            // col 0 is ring; write col 1 (hi half) only.
                            __half h1 = __float2half_rn(v1);
                            ((unsigned short*)nxt)[cell * 2 + 1] =
                                *(unsigned short*)&h1;
                        } else {
                            // u == 37: col 75 is ring; write col 74 (lo) only.
                            __half h0 = __float2half_rn(v0);
                            ((unsigned short*)nxt)[cell * 2] =
                                *(unsigned short*)&h0;
                        }
                    }
                } else {
                    // Direct global store of the core (pairs fully in-image).
                    if (u >= WH / 2 && u <= (WTC - 2 - WH) / 2 &&
                        r >= WH && r <= WTR - 1 - WH) {
                        float2 st; st.x = v0; st.y = v1;
                        *(float2*)(ob + gi * Wd + gj0) = st;
                    }
                }

                Ap = Ac; Bp = Bc; Cp = Cc;
                Ac = An; Bc = Bn; Cc = Cn;
            }
        }
        if (s < 6) {
            __syncthreads();
            unsigned* tmp = cur; cur = nxt; nxt = tmp;
        }
    }
}

// ---------------------------------------------------------------------------
// Workspace: T only (B*5*H*W half2 = 40 MB).
// ---------------------------------------------------------------------------
extern "C" void kernel_launch(void* const* d_in, const int* in_sizes, int n_in,
                              void* d_out, int out_size, void* d_ws, size_t ws_size,
                              hipStream_t stream) {
    const float* x  = (const float*)d_in[0];
    const float* Wu = (const float*)d_in[1];
    const float* bu = (const float*)d_in[2];
    float* out = (float*)d_out;
    __half2* T = (__half2*)d_ws;

    conv_step0_kernel<<<8192, CTH2, 0, stream>>>(x, Wu, bu, T, out);

    for (int t = 1; t < Td; ++t)
        fused6_pk_kernel<<<256, FTH, 0, stream>>>(out + (size_t)(t - 1) * HWc, T,
                                                  out + (size_t)t * HWc);
}